// Round 2
// baseline (90.082 us; speedup 1.0000x reference)
//
#include <hip/hip_runtime.h>

// Linear attention, fp32. N=8, L=S=8192, H=8, D=Dv=32.
// out[n,l,h,v] = (sum_d phiQ[l,d]*KV[d][v]) * 1/(sum_d phiQ[l,d]*Ksum[d] + 1e-6)
// where KV[d][v] = sum_s phiK[s,d]*values[s,v]  (the /S and *S of the reference
// cancel exactly: S is a power of two).
//
// R2: phase2 rebuilt — KV is block-uniform, so it is streamed through SGPRs
// via s_load_dwordx16 (scalar cache) instead of LDS broadcast reads. R1 showed
// phase2 was LDS-return-BW bound (8192 ds_read_b128/CU at ~20cyc = 67us).

#define N_      8
#define L_      8192
#define S_      8192
#define H_      8
#define D_      32
#define NH_     64            // N*H
#define CHUNKS_ 32            // s-chunks per (n,h) in phase 1
#define ROWS_   (S_ / CHUNKS_) // 256 rows per block
#define TILE_   64            // staged rows per LDS tile
#define KVE_    (D_ * D_)     // 1024
#define PKS_    (KVE_ + D_)   // 1056 floats: KV + Ksum

typedef float f32x16 __attribute__((ext_vector_type(16)));

__device__ __forceinline__ float phi_f(float x) {
    // elu(x)+1 : x>0 -> x+1 ; else exp(x)
    return x > 0.f ? x + 1.f : __expf(x);
}

// ---------------- Phase 1: KV + Ksum accumulation over s ----------------
template <bool ATOMIC>
__global__ __launch_bounds__(256) void la_phase1(
    const float* __restrict__ keys, const float* __restrict__ values,
    float* __restrict__ outp /* ATOMIC ? kvfinal[NH][PKS] : partials[NH][CHUNKS][PKS] */)
{
    __shared__ float kT[TILE_][D_];
    __shared__ float vT[TILE_][D_];
    const int nh    = blockIdx.x;   // 0..63
    const int chunk = blockIdx.y;   // 0..31
    const int n = nh >> 3, h = nh & 7;
    const int t  = threadIdx.x;
    const int d  = t & 31;          // this thread's K-dim
    const int vg = t >> 5;          // v-group: 4 consecutive v columns
    const size_t rs = (size_t)H_ * D_;   // 256 floats per (n,s) row
    const float* kbase = keys   + ((size_t)n * S_) * rs + (size_t)h * D_;
    const float* vbase = values + ((size_t)n * S_) * rs + (size_t)h * D_;
    const int s0 = chunk * ROWS_;

    float a0 = 0.f, a1 = 0.f, a2 = 0.f, a3 = 0.f, ksum = 0.f;

    for (int tb = 0; tb < ROWS_; tb += TILE_) {
        __syncthreads();
        // stage 64 rows of K (phi applied) and V; coalesced: 8 threads per row
#pragma unroll
        for (int i = 0; i < 2; ++i) {
            const int f   = t + i * 256;      // 0..511
            const int row = f >> 3;           // 0..63
            const int col = (f & 7) << 2;     // 0,4,...,28
            const size_t g = (size_t)(s0 + tb + row) * rs + col;
            const float4 k4 = *(const float4*)(kbase + g);
            const float4 v4 = *(const float4*)(vbase + g);
            *(float4*)&kT[row][col] =
                make_float4(phi_f(k4.x), phi_f(k4.y), phi_f(k4.z), phi_f(k4.w));
            *(float4*)&vT[row][col] = v4;
        }
        __syncthreads();
#pragma unroll 16
        for (int s = 0; s < TILE_; ++s) {
            const float  kk = kT[s][d];                        // b32, lanes->banks 0..31
            const float4 vv = *(const float4*)&vT[s][vg << 2]; // broadcast b128
            a0 = fmaf(kk, vv.x, a0);
            a1 = fmaf(kk, vv.y, a1);
            a2 = fmaf(kk, vv.z, a2);
            a3 = fmaf(kk, vv.w, a3);
            ksum += kk;   // identical across vg groups; only vg==0 stores it
        }
    }

    const int o = d * D_ + (vg << 2);
    if (ATOMIC) {
        float* p = outp + (size_t)nh * PKS_;
        atomicAdd(&p[o + 0], a0);
        atomicAdd(&p[o + 1], a1);
        atomicAdd(&p[o + 2], a2);
        atomicAdd(&p[o + 3], a3);
        if (vg == 0) atomicAdd(&p[KVE_ + d], ksum);
    } else {
        float* p = outp + ((size_t)nh * CHUNKS_ + chunk) * PKS_;
        *(float4*)&p[o] = make_float4(a0, a1, a2, a3);
        if (vg == 0) p[KVE_ + d] = ksum;
    }
}

// ---------------- Phase 1b: deterministic 32-way partial reduce ----------------
__global__ __launch_bounds__(256) void la_reduce(
    const float* __restrict__ partials, float* __restrict__ kvf)
{
    const int nh = blockIdx.x;
    for (int e = threadIdx.x; e < PKS_; e += 256) {
        const float* p = partials + (size_t)nh * CHUNKS_ * PKS_ + e;
        float s = 0.f;
#pragma unroll
        for (int c = 0; c < CHUNKS_; ++c) s += p[(size_t)c * PKS_];
        kvf[(size_t)nh * PKS_ + e] = s;
    }
}

__global__ void la_zero(float* __restrict__ p, int nelem) {
    const int i = blockIdx.x * 256 + threadIdx.x;
    if (i < nelem) p[i] = 0.f;
}

// ---------------- Phase 2: out = (phiQ . KV) * z, KV in SGPRs ----------------
// Loads 32 floats (one KV row) per asm block via 2x s_load_dwordx16 + wait.
// The wait is inside the same asm that defines the outputs, so any consumer
// is ordered after it by SSA dependence (no rule-18 hoist hazard).
#define SLOAD_ROW(lo, hi, base, byteoff)                                   \
    asm volatile("s_load_dwordx16 %0, %2, %3\n\t"                          \
                 "s_load_dwordx16 %1, %2, %4\n\t"                          \
                 "s_waitcnt lgkmcnt(0)"                                    \
                 : "=s"(lo), "=s"(hi)                                      \
                 : "s"(base), "i"(byteoff), "i"((byteoff) + 64))

__global__ __launch_bounds__(256) void la_phase2(
    const float* __restrict__ queries, const float* __restrict__ kvf,
    float* __restrict__ out)
{
    const int nh = blockIdx.x;   // 0..63
    const int lc = blockIdx.y;   // 0..31
    const int n = nh >> 3, h = nh & 7;
    const int t = threadIdx.x;

    const float* kvbase = kvf + (size_t)nh * PKS_;

    const int l = lc * 256 + t;
    const float* qrow = queries + (((size_t)n * L_ + l) * H_ + h) * D_;

    float q[D_];
#pragma unroll
    for (int j = 0; j < 8; ++j) {
        const float4 q4 = *(const float4*)(qrow + (j << 2));
        q[4 * j + 0] = phi_f(q4.x);
        q[4 * j + 1] = phi_f(q4.y);
        q[4 * j + 2] = phi_f(q4.z);
        q[4 * j + 3] = phi_f(q4.w);
    }

    // z = 1/(q . Ksum + eps) ; Ksum lives at byte offset KVE_*4
    {
        f32x16 klo, khi;
        SLOAD_ROW(klo, khi, kvbase, KVE_ * 4);
        float dot = 0.f;
#pragma unroll
        for (int j = 0; j < 16; ++j) dot = fmaf(q[j], klo[j], dot);
#pragma unroll
        for (int j = 0; j < 16; ++j) dot = fmaf(q[16 + j], khi[j], dot);
        const float z = 1.f / (dot + 1e-6f);
#pragma unroll
        for (int dd = 0; dd < D_; ++dd) q[dd] *= z;   // fold normalization into Q
    }

    float acc[D_];
#pragma unroll
    for (int v = 0; v < D_; ++v) acc[v] = 0.f;

#pragma unroll
    for (int dd = 0; dd < D_; ++dd) {
        f32x16 lo, hi;                       // KV row dd: 32 floats in SGPRs
        SLOAD_ROW(lo, hi, kvbase, dd * 128);
        const float qd = q[dd];
#pragma unroll
        for (int j = 0; j < 16; ++j) acc[j]      = fmaf(qd, lo[j], acc[j]);
#pragma unroll
        for (int j = 0; j < 16; ++j) acc[16 + j] = fmaf(qd, hi[j], acc[16 + j]);
    }

    float* orow = out + (((size_t)n * L_ + l) * H_ + h) * D_;
#pragma unroll
    for (int j = 0; j < 8; ++j)
        *(float4*)(orow + (j << 2)) =
            make_float4(acc[4 * j], acc[4 * j + 1], acc[4 * j + 2], acc[4 * j + 3]);
}

extern "C" void kernel_launch(void* const* d_in, const int* in_sizes, int n_in,
                              void* d_out, int out_size, void* d_ws, size_t ws_size,
                              hipStream_t stream)
{
    const float* queries = (const float*)d_in[0];
    const float* keys    = (const float*)d_in[1];
    const float* values  = (const float*)d_in[2];
    float* out = (float*)d_out;
    float* ws  = (float*)d_ws;

    const size_t partial_elems = (size_t)NH_ * CHUNKS_ * PKS_; // 2,162,688 floats
    const size_t final_elems   = (size_t)NH_ * PKS_;           // 67,584 floats
    const dim3 grid(NH_, CHUNKS_), blk(256);

    if (ws_size >= (partial_elems + final_elems) * sizeof(float)) {
        // deterministic two-stage reduction
        float* partials = ws;
        float* kvf      = ws + partial_elems;
        la_phase1<false><<<grid, blk, 0, stream>>>(keys, values, partials);
        la_reduce<<<dim3(NH_), blk, 0, stream>>>(partials, kvf);
        la_phase2<<<grid, blk, 0, stream>>>(queries, kvf, out);
    } else {
        // fallback: atomic accumulation into zeroed final buffer
        float* kvf = ws;
        const int nz = (int)final_elems;
        la_zero<<<dim3((nz + 255) / 256), blk, 0, stream>>>(kvf, nz);
        la_phase1<true><<<grid, blk, 0, stream>>>(keys, values, kvf);
        la_phase2<<<grid, blk, 0, stream>>>(queries, kvf, out);
    }
}

// Round 3
// 84.076 us; speedup vs baseline: 1.0714x; 1.0714x over previous
//
#include <hip/hip_runtime.h>

// Linear attention, fp32. N=8, L=S=8192, H=8, D=Dv=32.
// out[n,l,h,v] = (sum_d phiQ[l,d]*KV[d][v]) * 1/(sum_d phiQ[l,d]*Ksum[d] + 1e-6)
// where KV[d][v] = sum_s phiK[s,d]*values[s,v]  (the /S and *S of the reference
// cancel exactly: S is a power of two).
//
// R3: phase2 global access coalesced via LDS transpose staging (R1/R2 were
// transaction-bound: 64 lanes x 1KB stride = 64 txns/instr). KV stays in
// SGPRs via s_load_dwordx16, now 2 rows per waitcnt.

#define N_      8
#define L_      8192
#define S_      8192
#define H_      8
#define D_      32
#define NH_     64            // N*H
#define CHUNKS_ 32            // s-chunks per (n,h) in phase 1
#define ROWS_   (S_ / CHUNKS_) // 256 rows per block
#define TILE_   64            // staged rows per LDS tile
#define KVE_    (D_ * D_)     // 1024
#define PKS_    (KVE_ + D_)   // 1056 floats: KV + Ksum
#define QPAD_   33            // LDS row stride (floats): bank = (t + 4j) % 32

typedef float f32x16 __attribute__((ext_vector_type(16)));

__device__ __forceinline__ float phi_f(float x) {
    // elu(x)+1 : x>0 -> x+1 ; else exp(x)
    return x > 0.f ? x + 1.f : __expf(x);
}

// ---------------- Phase 1: KV + Ksum accumulation over s ----------------
template <bool ATOMIC>
__global__ __launch_bounds__(256) void la_phase1(
    const float* __restrict__ keys, const float* __restrict__ values,
    float* __restrict__ outp /* ATOMIC ? kvfinal[NH][PKS] : partials[NH][CHUNKS][PKS] */)
{
    __shared__ float kT[TILE_][D_];
    __shared__ float vT[TILE_][D_];
    const int nh    = blockIdx.x;   // 0..63
    const int chunk = blockIdx.y;   // 0..31
    const int n = nh >> 3, h = nh & 7;
    const int t  = threadIdx.x;
    const int d  = t & 31;          // this thread's K-dim
    const int vg = t >> 5;          // v-group: 4 consecutive v columns
    const size_t rs = (size_t)H_ * D_;   // 256 floats per (n,s) row
    const float* kbase = keys   + ((size_t)n * S_) * rs + (size_t)h * D_;
    const float* vbase = values + ((size_t)n * S_) * rs + (size_t)h * D_;
    const int s0 = chunk * ROWS_;

    float a0 = 0.f, a1 = 0.f, a2 = 0.f, a3 = 0.f, ksum = 0.f;

    for (int tb = 0; tb < ROWS_; tb += TILE_) {
        __syncthreads();
        // stage 64 rows of K (phi applied) and V; coalesced: 8 threads per row
#pragma unroll
        for (int i = 0; i < 2; ++i) {
            const int f   = t + i * 256;      // 0..511
            const int row = f >> 3;           // 0..63
            const int col = (f & 7) << 2;     // 0,4,...,28
            const size_t g = (size_t)(s0 + tb + row) * rs + col;
            const float4 k4 = *(const float4*)(kbase + g);
            const float4 v4 = *(const float4*)(vbase + g);
            *(float4*)&kT[row][col] =
                make_float4(phi_f(k4.x), phi_f(k4.y), phi_f(k4.z), phi_f(k4.w));
            *(float4*)&vT[row][col] = v4;
        }
        __syncthreads();
#pragma unroll 16
        for (int s = 0; s < TILE_; ++s) {
            const float  kk = kT[s][d];                        // b32, lanes->banks 0..31
            const float4 vv = *(const float4*)&vT[s][vg << 2]; // broadcast b128
            a0 = fmaf(kk, vv.x, a0);
            a1 = fmaf(kk, vv.y, a1);
            a2 = fmaf(kk, vv.z, a2);
            a3 = fmaf(kk, vv.w, a3);
            ksum += kk;   // identical across vg groups; only vg==0 stores it
        }
    }

    const int o = d * D_ + (vg << 2);
    if (ATOMIC) {
        float* p = outp + (size_t)nh * PKS_;
        atomicAdd(&p[o + 0], a0);
        atomicAdd(&p[o + 1], a1);
        atomicAdd(&p[o + 2], a2);
        atomicAdd(&p[o + 3], a3);
        if (vg == 0) atomicAdd(&p[KVE_ + d], ksum);
    } else {
        float* p = outp + ((size_t)nh * CHUNKS_ + chunk) * PKS_;
        *(float4*)&p[o] = make_float4(a0, a1, a2, a3);
        if (vg == 0) p[KVE_ + d] = ksum;
    }
}

// ---------------- Phase 1b: deterministic 32-way partial reduce ----------------
__global__ __launch_bounds__(256) void la_reduce(
    const float* __restrict__ partials, float* __restrict__ kvf)
{
    const int nh = blockIdx.x;
    for (int e = threadIdx.x; e < PKS_; e += 256) {
        const float* p = partials + (size_t)nh * CHUNKS_ * PKS_ + e;
        float s = 0.f;
#pragma unroll
        for (int c = 0; c < CHUNKS_; ++c) s += p[(size_t)c * PKS_];
        kvf[(size_t)nh * PKS_ + e] = s;
    }
}

__global__ void la_zero(float* __restrict__ p, int nelem) {
    const int i = blockIdx.x * 256 + threadIdx.x;
    if (i < nelem) p[i] = 0.f;
}

// One KV row (32 floats) into SGPRs; wait inside the defining asm so SSA
// dependence orders consumers after the wait.
#define SLOAD_ROW(lo, hi, base, byteoff)                                   \
    asm volatile("s_load_dwordx16 %0, %2, %3\n\t"                          \
                 "s_load_dwordx16 %1, %2, %4\n\t"                          \
                 "s_waitcnt lgkmcnt(0)"                                    \
                 : "=s"(lo), "=s"(hi)                                      \
                 : "s"(base), "i"(byteoff), "i"((byteoff) + 64))

// Two KV rows per wait: 4 loads pipelined, one stall.
#define SLOAD_2ROWS(r0, r1, r2, r3, base, byteoff)                         \
    asm volatile("s_load_dwordx16 %0, %4, %5\n\t"                          \
                 "s_load_dwordx16 %1, %4, %6\n\t"                          \
                 "s_load_dwordx16 %2, %4, %7\n\t"                          \
                 "s_load_dwordx16 %3, %4, %8\n\t"                          \
                 "s_waitcnt lgkmcnt(0)"                                    \
                 : "=s"(r0), "=s"(r1), "=s"(r2), "=s"(r3)                  \
                 : "s"(base), "i"(byteoff), "i"((byteoff) + 64),           \
                   "i"((byteoff) + 128), "i"((byteoff) + 192))

// ---------------- Phase 2: out = (phiQ . KV) * z ----------------
// Coalesced global I/O via LDS transpose staging; KV in SGPRs.
__global__ __launch_bounds__(256) void la_phase2(
    const float* __restrict__ queries, const float* __restrict__ kvf,
    float* __restrict__ out)
{
    __shared__ float qs[256][QPAD_];
    const int nh = blockIdx.x;   // 0..63
    const int lc = blockIdx.y;   // 0..31
    const int n = nh >> 3, h = nh & 7;
    const int t = threadIdx.x;
    const size_t rs = (size_t)H_ * D_;   // 256 floats per (n,l) row

    const float* kvbase = kvf + (size_t)nh * PKS_;
    const size_t tbase = (((size_t)n * L_ + (size_t)lc * 256) * H_ + h) * D_;
    const float* qtile = queries + tbase;

    // ---- coalesced load + phi + transpose into LDS ----
#pragma unroll
    for (int i = 0; i < 8; ++i) {
        const int f   = t + i * 256;     // 0..2047
        const int row = f >> 3;          // 0..255
        const int col = (f & 7) << 2;    // 0..28
        const float4 q4 = *(const float4*)(qtile + (size_t)row * rs + col);
        *(float4*)&qs[row][col] =
            make_float4(phi_f(q4.x), phi_f(q4.y), phi_f(q4.z), phi_f(q4.w));
    }
    __syncthreads();

    // ---- own row -> registers (bank-conflict-free: (t + 4j) % 32) ----
    float q[D_];
#pragma unroll
    for (int j = 0; j < 8; ++j) {
        const float4 q4 = *(const float4*)&qs[t][j << 2];
        q[4 * j + 0] = q4.x; q[4 * j + 1] = q4.y;
        q[4 * j + 2] = q4.z; q[4 * j + 3] = q4.w;
    }

    // ---- z = 1/(q . Ksum + eps), folded into q ----
    {
        f32x16 klo, khi;
        SLOAD_ROW(klo, khi, kvbase, KVE_ * 4);
        float dot = 0.f;
#pragma unroll
        for (int j = 0; j < 16; ++j) dot = fmaf(q[j], klo[j], dot);
#pragma unroll
        for (int j = 0; j < 16; ++j) dot = fmaf(q[16 + j], khi[j], dot);
        const float z = 1.f / (dot + 1e-6f);
#pragma unroll
        for (int dd = 0; dd < D_; ++dd) q[dd] *= z;
    }

    // ---- matvec: acc[v] += q[dd] * KV[dd][v], KV rows streamed via SGPRs ----
    float acc[D_];
#pragma unroll
    for (int v = 0; v < D_; ++v) acc[v] = 0.f;

#pragma unroll
    for (int dd = 0; dd < D_; dd += 2) {
        f32x16 a0, a1, b0, b1;
        SLOAD_2ROWS(a0, a1, b0, b1, kvbase, dd * 128);
        const float qa = q[dd], qb = q[dd + 1];
#pragma unroll
        for (int j = 0; j < 16; ++j) acc[j]      = fmaf(qa, a0[j], acc[j]);
#pragma unroll
        for (int j = 0; j < 16; ++j) acc[16 + j] = fmaf(qa, a1[j], acc[16 + j]);
#pragma unroll
        for (int j = 0; j < 16; ++j) acc[j]      = fmaf(qb, b0[j], acc[j]);
#pragma unroll
        for (int j = 0; j < 16; ++j) acc[16 + j] = fmaf(qb, b1[j], acc[16 + j]);
    }

    // ---- stage acc into own LDS row (only this thread ever read row t) ----
#pragma unroll
    for (int j = 0; j < 8; ++j)
        *(float4*)&qs[t][j << 2] =
            make_float4(acc[4 * j], acc[4 * j + 1], acc[4 * j + 2], acc[4 * j + 3]);
    __syncthreads();

    // ---- coalesced transposed store ----
    float* otile = out + tbase;
#pragma unroll
    for (int i = 0; i < 8; ++i) {
        const int f   = t + i * 256;
        const int row = f >> 3;
        const int col = (f & 7) << 2;
        *(float4*)(otile + (size_t)row * rs + col) = *(const float4*)&qs[row][col];
    }
}

extern "C" void kernel_launch(void* const* d_in, const int* in_sizes, int n_in,
                              void* d_out, int out_size, void* d_ws, size_t ws_size,
                              hipStream_t stream)
{
    const float* queries = (const float*)d_in[0];
    const float* keys    = (const float*)d_in[1];
    const float* values  = (const float*)d_in[2];
    float* out = (float*)d_out;
    float* ws  = (float*)d_ws;

    const size_t partial_elems = (size_t)NH_ * CHUNKS_ * PKS_; // 2,162,688 floats
    const size_t final_elems   = (size_t)NH_ * PKS_;           // 67,584 floats
    const dim3 grid(NH_, CHUNKS_), blk(256);

    if (ws_size >= (partial_elems + final_elems) * sizeof(float)) {
        // deterministic two-stage reduction
        float* partials = ws;
        float* kvf      = ws + partial_elems;
        la_phase1<false><<<grid, blk, 0, stream>>>(keys, values, partials);
        la_reduce<<<dim3(NH_), blk, 0, stream>>>(partials, kvf);
        la_phase2<<<grid, blk, 0, stream>>>(queries, kvf, out);
    } else {
        // fallback: atomic accumulation into zeroed final buffer
        float* kvf = ws;
        const int nz = (int)final_elems;
        la_zero<<<dim3((nz + 255) / 256), blk, 0, stream>>>(kvf, nz);
        la_phase1<true><<<grid, blk, 0, stream>>>(keys, values, kvf);
        la_phase2<<<grid, blk, 0, stream>>>(queries, kvf, out);
    }
}

// Round 4
// 81.337 us; speedup vs baseline: 1.1075x; 1.0337x over previous
//
#include <hip/hip_runtime.h>

// Linear attention, fp32. N=8, L=S=8192, H=8, D=Dv=32.
// out[n,l,h,v] = (sum_d phiQ[l,d]*KV[d][v]) * 1/(sum_d phiQ[l,d]*Ksum[d] + 1e-6)
// where KV[d][v] = sum_s phiK[s,d]*values[s,v]  (the /S and *S of the reference
// cancel exactly: S is a power of two).
//
// R4: phase2 register-blocked. R1-R3 all ~67-70us despite different operand
// paths -> common cost was re-fetching the whole 4KB KV per output row
// (LDS broadcast or serialized SMEM). Now: thread (slice=t&7, group=t>>3)
// holds KV[:, 4s..4s+3] in 128 VGPRs ONCE, reused across 8 rows; Ksum in
// SGPRs; phiQ rows broadcast from LDS (8 ds_read_b128/row).

#define N_      8
#define L_      8192
#define S_      8192
#define H_      8
#define D_      32
#define NH_     64            // N*H
#define CHUNKS_ 32            // s-chunks per (n,h) in phase 1
#define ROWS_   (S_ / CHUNKS_) // 256 rows per block
#define TILE_   64            // staged rows per LDS tile
#define KVE_    (D_ * D_)     // 1024
#define PKS_    (KVE_ + D_)   // 1056 floats: KV + Ksum
#define QPAD_   33            // LDS row stride (floats)

typedef float f32x16 __attribute__((ext_vector_type(16)));

__device__ __forceinline__ float phi_f(float x) {
    // elu(x)+1 : x>0 -> x+1 ; else exp(x)
    return x > 0.f ? x + 1.f : __expf(x);
}

// ---------------- Phase 1: KV + Ksum accumulation over s ----------------
template <bool ATOMIC>
__global__ __launch_bounds__(256) void la_phase1(
    const float* __restrict__ keys, const float* __restrict__ values,
    float* __restrict__ outp /* ATOMIC ? kvfinal[NH][PKS] : partials[NH][CHUNKS][PKS] */)
{
    __shared__ float kT[TILE_][D_];
    __shared__ float vT[TILE_][D_];
    const int nh    = blockIdx.x;   // 0..63
    const int chunk = blockIdx.y;   // 0..31
    const int n = nh >> 3, h = nh & 7;
    const int t  = threadIdx.x;
    const int d  = t & 31;          // this thread's K-dim
    const int vg = t >> 5;          // v-group: 4 consecutive v columns
    const size_t rs = (size_t)H_ * D_;   // 256 floats per (n,s) row
    const float* kbase = keys   + ((size_t)n * S_) * rs + (size_t)h * D_;
    const float* vbase = values + ((size_t)n * S_) * rs + (size_t)h * D_;
    const int s0 = chunk * ROWS_;

    float a0 = 0.f, a1 = 0.f, a2 = 0.f, a3 = 0.f, ksum = 0.f;

    for (int tb = 0; tb < ROWS_; tb += TILE_) {
        __syncthreads();
        // stage 64 rows of K (phi applied) and V; coalesced: 8 threads per row
#pragma unroll
        for (int i = 0; i < 2; ++i) {
            const int f   = t + i * 256;      // 0..511
            const int row = f >> 3;           // 0..63
            const int col = (f & 7) << 2;     // 0,4,...,28
            const size_t g = (size_t)(s0 + tb + row) * rs + col;
            const float4 k4 = *(const float4*)(kbase + g);
            const float4 v4 = *(const float4*)(vbase + g);
            *(float4*)&kT[row][col] =
                make_float4(phi_f(k4.x), phi_f(k4.y), phi_f(k4.z), phi_f(k4.w));
            *(float4*)&vT[row][col] = v4;
        }
        __syncthreads();
#pragma unroll 16
        for (int s = 0; s < TILE_; ++s) {
            const float  kk = kT[s][d];                        // b32, lanes->banks 0..31
            const float4 vv = *(const float4*)&vT[s][vg << 2]; // broadcast b128
            a0 = fmaf(kk, vv.x, a0);
            a1 = fmaf(kk, vv.y, a1);
            a2 = fmaf(kk, vv.z, a2);
            a3 = fmaf(kk, vv.w, a3);
            ksum += kk;   // identical across vg groups; only vg==0 stores it
        }
    }

    const int o = d * D_ + (vg << 2);
    if (ATOMIC) {
        float* p = outp + (size_t)nh * PKS_;
        atomicAdd(&p[o + 0], a0);
        atomicAdd(&p[o + 1], a1);
        atomicAdd(&p[o + 2], a2);
        atomicAdd(&p[o + 3], a3);
        if (vg == 0) atomicAdd(&p[KVE_ + d], ksum);
    } else {
        float* p = outp + ((size_t)nh * CHUNKS_ + chunk) * PKS_;
        *(float4*)&p[o] = make_float4(a0, a1, a2, a3);
        if (vg == 0) p[KVE_ + d] = ksum;
    }
}

// ---------------- Phase 1b: deterministic 32-way partial reduce ----------------
__global__ __launch_bounds__(256) void la_reduce(
    const float* __restrict__ partials, float* __restrict__ kvf)
{
    const int nh = blockIdx.x;
    for (int e = threadIdx.x; e < PKS_; e += 256) {
        const float* p = partials + (size_t)nh * CHUNKS_ * PKS_ + e;
        float s = 0.f;
#pragma unroll
        for (int c = 0; c < CHUNKS_; ++c) s += p[(size_t)c * PKS_];
        kvf[(size_t)nh * PKS_ + e] = s;
    }
}

__global__ void la_zero(float* __restrict__ p, int nelem) {
    const int i = blockIdx.x * 256 + threadIdx.x;
    if (i < nelem) p[i] = 0.f;
}

// Ksum (32 floats) into SGPRs; wait inside the defining asm so SSA dependence
// orders consumers after the wait.
#define SLOAD_ROW(lo, hi, base, byteoff)                                   \
    asm volatile("s_load_dwordx16 %0, %2, %3\n\t"                          \
                 "s_load_dwordx16 %1, %2, %4\n\t"                          \
                 "s_waitcnt lgkmcnt(0)"                                    \
                 : "=s"(lo), "=s"(hi)                                      \
                 : "s"(base), "i"(byteoff), "i"((byteoff) + 64))

// ---------------- Phase 2: out = (phiQ . KV) * z, KV register-blocked ----------
__global__ __launch_bounds__(256, 2) void la_phase2(
    const float* __restrict__ queries, const float* __restrict__ kvf,
    float* __restrict__ out)
{
    __shared__ float qs[256][QPAD_];
    const int nh = blockIdx.x;   // 0..63
    const int lc = blockIdx.y;   // 0..31
    const int n = nh >> 3, h = nh & 7;
    const int t = threadIdx.x;
    const int slice = t & 7;     // v-columns [4*slice, 4*slice+4)
    const int g8    = (t >> 3) << 3;  // first of this thread's 8 rows
    const size_t rs = (size_t)H_ * D_;   // 256 floats per (n,l) row

    const float* kvbase = kvf + (size_t)nh * PKS_;
    const size_t tbase = (((size_t)n * L_ + (size_t)lc * 256) * H_ + h) * D_;
    const float* qtile = queries + tbase;

    // ---- Ksum -> SGPRs (uniform) ----
    f32x16 klo, khi;
    SLOAD_ROW(klo, khi, kvbase, KVE_ * 4);

    // ---- coalesced load + phi + transpose into LDS ----
#pragma unroll
    for (int i = 0; i < 8; ++i) {
        const int f   = t + i * 256;     // 0..2047
        const int row = f >> 3;          // 0..255
        const int col = (f & 7) << 2;    // 0..28
        const float4 q4 = *(const float4*)(qtile + (size_t)row * rs + col);
        *(float4*)&qs[row][col] =
            make_float4(phi_f(q4.x), phi_f(q4.y), phi_f(q4.z), phi_f(q4.w));
    }

    // ---- KV column slice -> 128 VGPRs (loaded once, reused for 8 rows) ----
    float4 kv[D_];
#pragma unroll
    for (int dd = 0; dd < D_; ++dd)
        kv[dd] = *(const float4*)(kvbase + dd * D_ + (slice << 2));

    __syncthreads();

    float* otile = out + tbase;

    // ---- 8 rows: q from LDS broadcast, acc in VGPRs against kv[] ----
#pragma unroll
    for (int r = 0; r < 8; ++r) {
        const int row = g8 + r;
        float a0 = 0.f, a1 = 0.f, a2 = 0.f, a3 = 0.f, dot = 0.f;
#pragma unroll
        for (int j = 0; j < 4; ++j) {          // d = 4j .. 4j+3 (Ksum in klo)
            const float4 q4 = *(const float4*)&qs[row][j << 2];
            dot = fmaf(q4.x, klo[4 * j + 0], dot);
            dot = fmaf(q4.y, klo[4 * j + 1], dot);
            dot = fmaf(q4.z, klo[4 * j + 2], dot);
            dot = fmaf(q4.w, klo[4 * j + 3], dot);
            const float4 k0 = kv[4 * j + 0], k1 = kv[4 * j + 1];
            const float4 k2 = kv[4 * j + 2], k3 = kv[4 * j + 3];
            a0 = fmaf(q4.x, k0.x, a0); a1 = fmaf(q4.x, k0.y, a1);
            a2 = fmaf(q4.x, k0.z, a2); a3 = fmaf(q4.x, k0.w, a3);
            a0 = fmaf(q4.y, k1.x, a0); a1 = fmaf(q4.y, k1.y, a1);
            a2 = fmaf(q4.y, k1.z, a2); a3 = fmaf(q4.y, k1.w, a3);
            a0 = fmaf(q4.z, k2.x, a0); a1 = fmaf(q4.z, k2.y, a1);
            a2 = fmaf(q4.z, k2.z, a2); a3 = fmaf(q4.z, k2.w, a3);
            a0 = fmaf(q4.w, k3.x, a0); a1 = fmaf(q4.w, k3.y, a1);
            a2 = fmaf(q4.w, k3.z, a2); a3 = fmaf(q4.w, k3.w, a3);
        }
#pragma unroll
        for (int j = 4; j < 8; ++j) {          // d = 4j .. 4j+3 (Ksum in khi)
            const float4 q4 = *(const float4*)&qs[row][j << 2];
            dot = fmaf(q4.x, khi[4 * j - 16], dot);
            dot = fmaf(q4.y, khi[4 * j - 15], dot);
            dot = fmaf(q4.z, khi[4 * j - 14], dot);
            dot = fmaf(q4.w, khi[4 * j - 13], dot);
            const float4 k0 = kv[4 * j + 0], k1 = kv[4 * j + 1];
            const float4 k2 = kv[4 * j + 2], k3 = kv[4 * j + 3];
            a0 = fmaf(q4.x, k0.x, a0); a1 = fmaf(q4.x, k0.y, a1);
            a2 = fmaf(q4.x, k0.z, a2); a3 = fmaf(q4.x, k0.w, a3);
            a0 = fmaf(q4.y, k1.x, a0); a1 = fmaf(q4.y, k1.y, a1);
            a2 = fmaf(q4.y, k1.z, a2); a3 = fmaf(q4.y, k1.w, a3);
            a0 = fmaf(q4.z, k2.x, a0); a1 = fmaf(q4.z, k2.y, a1);
            a2 = fmaf(q4.z, k2.z, a2); a3 = fmaf(q4.z, k2.w, a3);
            a0 = fmaf(q4.w, k3.x, a0); a1 = fmaf(q4.w, k3.y, a1);
            a2 = fmaf(q4.w, k3.z, a2); a3 = fmaf(q4.w, k3.w, a3);
        }
        const float z = 1.f / (dot + 1e-6f);
        *(float4*)(otile + (size_t)row * rs + (slice << 2)) =
            make_float4(a0 * z, a1 * z, a2 * z, a3 * z);
    }
}

extern "C" void kernel_launch(void* const* d_in, const int* in_sizes, int n_in,
                              void* d_out, int out_size, void* d_ws, size_t ws_size,
                              hipStream_t stream)
{
    const float* queries = (const float*)d_in[0];
    const float* keys    = (const float*)d_in[1];
    const float* values  = (const float*)d_in[2];
    float* out = (float*)d_out;
    float* ws  = (float*)d_ws;

    const size_t partial_elems = (size_t)NH_ * CHUNKS_ * PKS_; // 2,162,688 floats
    const size_t final_elems   = (size_t)NH_ * PKS_;           // 67,584 floats
    const dim3 grid(NH_, CHUNKS_), blk(256);

    if (ws_size >= (partial_elems + final_elems) * sizeof(float)) {
        // deterministic two-stage reduction
        float* partials = ws;
        float* kvf      = ws + partial_elems;
        la_phase1<false><<<grid, blk, 0, stream>>>(keys, values, partials);
        la_reduce<<<dim3(NH_), blk, 0, stream>>>(partials, kvf);
        la_phase2<<<grid, blk, 0, stream>>>(queries, kvf, out);
    } else {
        // fallback: atomic accumulation into zeroed final buffer
        float* kvf = ws;
        const int nz = (int)final_elems;
        la_zero<<<dim3((nz + 255) / 256), blk, 0, stream>>>(kvf, nz);
        la_phase1<true><<<grid, blk, 0, stream>>>(keys, values, kvf);
        la_phase2<<<grid, blk, 0, stream>>>(queries, kvf, out);
    }
}